// Round 1
// baseline (2932.890 us; speedup 1.0000x reference)
//
#include <hip/hip_runtime.h>
#include <hip/hip_bf16.h>

#define LRELU_SLOPE 0.2f

__device__ __forceinline__ float lrelu(float x) { return x > 0.f ? x : LRELU_SLOPE * x; }

// ---------------- utility kernels ----------------
__global__ void k_zero(int* __restrict__ a, int n) {
    int i = blockIdx.x * blockDim.x + threadIdx.x;
    if (i < n) a[i] = 0;
}

__global__ void k_hist(const int* __restrict__ dst, int* __restrict__ deg, int E) {
    int i = blockIdx.x * blockDim.x + threadIdx.x;
    if (i < E) atomicAdd(&deg[dst[i]], 1);
}

// block-level exclusive scan over 1024 elements; writes per-block totals
__global__ __launch_bounds__(1024) void k_scan1(const int* __restrict__ deg, int* __restrict__ off,
                                                int* __restrict__ bsums, int N) {
    int t = threadIdx.x, b = blockIdx.x;
    int idx = b * 1024 + t;
    int v = (idx < N) ? deg[idx] : 0;
    int lane = t & 63, wid = t >> 6;
    int incl = v;
    #pragma unroll
    for (int d = 1; d < 64; d <<= 1) {
        int u = __shfl_up(incl, d);
        if (lane >= d) incl += u;
    }
    __shared__ int ws[16];
    if (lane == 63) ws[wid] = incl;
    __syncthreads();
    if (wid == 0) {
        int wv = (lane < 16) ? ws[lane] : 0;
        #pragma unroll
        for (int d = 1; d < 16; d <<= 1) {
            int u = __shfl_up(wv, d);
            if (lane >= d) wv += u;
        }
        if (lane < 16) ws[lane] = wv;  // inclusive wave sums
    }
    __syncthreads();
    int woff = (wid > 0) ? ws[wid - 1] : 0;
    if (idx < N) off[idx] = woff + incl - v;  // exclusive within block
    if (t == 0) bsums[b] = ws[15];            // block total
}

// single-block exclusive scan of up to 1024 block sums
__global__ __launch_bounds__(1024) void k_scan2(int* __restrict__ bs, int nb) {
    __shared__ int s[1024];
    int t = threadIdx.x;
    s[t] = (t < nb) ? bs[t] : 0;
    __syncthreads();
    for (int d = 1; d < 1024; d <<= 1) {
        int v = (t >= d) ? s[t - d] : 0;
        __syncthreads();
        s[t] += v;
        __syncthreads();
    }
    if (t < nb) bs[t] = t ? s[t - 1] : 0;
}

__global__ __launch_bounds__(1024) void k_scan3(int* __restrict__ off, const int* __restrict__ bs, int N) {
    int i = blockIdx.x * 1024 + threadIdx.x;
    if (i < N) off[i] += bs[blockIdx.x];
}

__global__ void k_scatter(const int* __restrict__ src, const int* __restrict__ dst,
                          const int* __restrict__ off, int* __restrict__ cur,
                          int* __restrict__ csr, int E) {
    int i = blockIdx.x * blockDim.x + threadIdx.x;
    if (i < E) {
        int d = dst[i];
        int pos = off[d] + atomicAdd(&cur[d], 1);
        csr[pos] = src[i];
    }
}

// ---------------- GEMM: XW = X[N,K] @ W[K,64], fused attention logits ----------------
// One wave computes 4 rows; lane j owns output column j. W staged in LDS row-major
// [K][64] (consecutive lanes -> consecutive banks, 2-way conflict = free). x row held
// in registers, broadcast via fully-unrolled __shfl (v_readlane).
template <int K>
__global__ __launch_bounds__(256) void k_gemm(const float* __restrict__ X, const float* __restrict__ W,
                                              const float* __restrict__ a_s, const float* __restrict__ a_d,
                                              float* __restrict__ XW, float* __restrict__ Ssrc,
                                              float* __restrict__ Sdst, int N) {
    constexpr int EPL = K / 64;  // x elements held per lane
    __shared__ float Wl[K * 64];
    int t = threadIdx.x;
    for (int i = t; i < K * 64; i += 256) Wl[i] = W[i];
    __syncthreads();
    int lane = t & 63, wid = t >> 6;
    int rowBase = (blockIdx.x * 4 + wid) * 4;
    if (rowBase >= N) return;
    int nr = N - rowBase;
    if (nr > 4) nr = 4;

    float xv[4][EPL];
    #pragma unroll
    for (int r = 0; r < 4; r++) {
        int row = rowBase + (r < nr ? r : 0);
        if constexpr (EPL == 4) {
            const float4 v = *(const float4*)&X[(size_t)row * K + lane * 4];
            xv[r][0] = v.x; xv[r][1] = v.y; xv[r][2] = v.z; xv[r][3] = v.w;
        } else {
            xv[r][0] = X[(size_t)row * K + lane];
        }
    }

    float acc[4] = {0.f, 0.f, 0.f, 0.f};
    #pragma unroll
    for (int k = 0; k < K; k++) {
        float w = Wl[k * 64 + lane];
        #pragma unroll
        for (int r = 0; r < 4; r++) {
            float xk = __shfl(xv[r][k % EPL], k / EPL);
            acc[r] += xk * w;
        }
    }

    float as = a_s[lane], ad = a_d[lane];
    for (int r = 0; r < nr; r++) {
        int row = rowBase + r;
        XW[(size_t)row * 64 + lane] = acc[r];
        float vs = acc[r] * as, vd = acc[r] * ad;
        #pragma unroll
        for (int d = 32; d > 0; d >>= 1) {
            vs += __shfl_xor(vs, d);
            vd += __shfl_xor(vd, d);
        }
        if (lane == 0) { Ssrc[row] = vs; Sdst[row] = vd; }
    }
}

// ---------------- attention + aggregate: one wave per dst node ----------------
__global__ __launch_bounds__(256) void k_attn(const float* __restrict__ XW, const float* __restrict__ Ssrc,
                                              const float* __restrict__ Sdst, const int* __restrict__ csr,
                                              const int* __restrict__ off, const int* __restrict__ deg,
                                              const float* __restrict__ bias, float* __restrict__ H,
                                              int N, int do_relu) {
    int t = threadIdx.x, lane = t & 63, wid = t >> 6;
    int n = blockIdx.x * 4 + wid;
    if (n >= N) return;
    float sd = Sdst[n];
    int st = off[n], d = deg[n];

    // phase 1: max over edges (lanes parallel over edges); cache first 64 src/e in regs
    float eself = lrelu(Ssrc[n] + sd);
    float m = eself;
    int myS = 0;
    float myE = -1e30f;
    if (lane < d) {
        myS = csr[st + lane];
        myE = lrelu(Ssrc[myS] + sd);
        m = fmaxf(m, myE);
    }
    for (int i = 64 + lane; i < d; i += 64) {
        int s = csr[st + i];
        m = fmaxf(m, lrelu(Ssrc[s] + sd));
    }
    #pragma unroll
    for (int dd = 32; dd > 0; dd >>= 1) m = fmaxf(m, __shfl_xor(m, dd));

    // phase 2: serial over edges, lanes = feature dims
    float w0 = __expf(eself - m);
    float denom = w0;
    float acc = w0 * XW[(size_t)n * 64 + lane];
    int dcap = d < 64 ? d : 64;
    for (int i = 0; i < dcap; i++) {
        int s = __shfl(myS, i);
        float e = __shfl(myE, i);
        float w = __expf(e - m);
        denom += w;
        acc += w * XW[(size_t)s * 64 + lane];
    }
    for (int i = 64; i < d; i++) {
        int s = csr[st + i];
        float e = lrelu(Ssrc[s] + sd);
        float w = __expf(e - m);
        denom += w;
        acc += w * XW[(size_t)s * 64 + lane];
    }
    float o = acc / denom + bias[lane];
    if (do_relu) o = fmaxf(o, 0.f);
    H[(size_t)n * 64 + lane] = o;
}

// ---------------- head: out[i] = [h[u]; h[m]] . fcW + fcb ----------------
__global__ __launch_bounds__(256) void k_head(const float* __restrict__ H, const int* __restrict__ ui,
                                              const int* __restrict__ mi, const float* __restrict__ fcW,
                                              const float* __restrict__ fcb, float* __restrict__ out, int B) {
    int t = threadIdx.x, lane = t & 63, wid = t >> 6;
    int i = blockIdx.x * 4 + wid;
    if (i >= B) return;
    int u = ui[i], m = mi[i];
    float v = H[(size_t)u * 64 + lane] * fcW[lane] + H[(size_t)m * 64 + lane] * fcW[64 + lane];
    #pragma unroll
    for (int dd = 32; dd > 0; dd >>= 1) v += __shfl_xor(v, dd);
    if (lane == 0) out[i] = v + fcb[0];
}

extern "C" void kernel_launch(void* const* d_in, const int* in_sizes, int n_in,
                              void* d_out, int out_size, void* d_ws, size_t ws_size,
                              hipStream_t stream) {
    const float* x   = (const float*)d_in[0];
    const int*   ei  = (const int*)d_in[1];
    const int*   ui  = (const int*)d_in[2];
    const int*   mi  = (const int*)d_in[3];
    const float* W1  = (const float*)d_in[4];
    const float* as1 = (const float*)d_in[5];
    const float* ad1 = (const float*)d_in[6];
    const float* b1  = (const float*)d_in[7];
    const float* W2  = (const float*)d_in[8];
    const float* as2 = (const float*)d_in[9];
    const float* ad2 = (const float*)d_in[10];
    const float* b2  = (const float*)d_in[11];
    const float* fcW = (const float*)d_in[12];
    const float* fcb = (const float*)d_in[13];
    float* out = (float*)d_out;

    const int Hdim = in_sizes[5];            // 64
    const int FIN  = in_sizes[4] / Hdim;     // 256
    const int N    = in_sizes[0] / FIN;      // 100000
    const int E    = in_sizes[1] / 2;        // 1000000
    const int B    = in_sizes[2];            // 16384

    // workspace carve
    char* w = (char*)d_ws;
    auto alloc = [&](size_t bytes) -> void* {
        void* p = (void*)w;
        w += (bytes + 255) & ~(size_t)255;
        return p;
    };
    float* xw   = (float*)alloc((size_t)N * 64 * 4);
    float* hbuf = (float*)alloc((size_t)N * 64 * 4);
    float* ssrc = (float*)alloc((size_t)N * 4);
    float* sdst = (float*)alloc((size_t)N * 4);
    int* degcur = (int*)alloc((size_t)2 * N * 4);  // deg | cur contiguous
    int* deg = degcur;
    int* cur = degcur + N;
    int* offv  = (int*)alloc((size_t)N * 4);
    int* bsums = (int*)alloc((size_t)1024 * 4);
    int* csr   = (int*)alloc((size_t)E * 4);

    const int* esrc = ei;
    const int* edst = ei + E;

    // --- build CSR by dst (shared by both layers) ---
    k_zero<<<(2 * N + 1023) / 1024, 1024, 0, stream>>>(degcur, 2 * N);
    k_hist<<<(E + 255) / 256, 256, 0, stream>>>(edst, deg, E);
    int nb = (N + 1023) / 1024;
    k_scan1<<<nb, 1024, 0, stream>>>(deg, offv, bsums, N);
    k_scan2<<<1, 1024, 0, stream>>>(bsums, nb);
    k_scan3<<<nb, 1024, 0, stream>>>(offv, bsums, N);
    k_scatter<<<(E + 255) / 256, 256, 0, stream>>>(esrc, edst, offv, cur, csr, E);

    // --- layer 1 ---
    k_gemm<256><<<(N + 15) / 16, 256, 0, stream>>>(x, W1, as1, ad1, xw, ssrc, sdst, N);
    k_attn<<<(N + 3) / 4, 256, 0, stream>>>(xw, ssrc, sdst, csr, offv, deg, b1, hbuf, N, 1);

    // --- layer 2 (xw buffer reused) ---
    k_gemm<64><<<(N + 15) / 16, 256, 0, stream>>>(hbuf, W2, as2, ad2, xw, ssrc, sdst, N);
    k_attn<<<(N + 3) / 4, 256, 0, stream>>>(xw, ssrc, sdst, csr, offv, deg, b2, hbuf, N, 0);

    // --- head ---
    k_head<<<(B + 3) / 4, 256, 0, stream>>>(hbuf, ui, mi, fcW, fcb, out, B);
}

// Round 2
// 882.385 us; speedup vs baseline: 3.3238x; 3.3238x over previous
//
#include <hip/hip_runtime.h>
#include <hip/hip_bf16.h>

#define LRELU_SLOPE 0.2f

__device__ __forceinline__ float lrelu(float x) { return x > 0.f ? x : LRELU_SLOPE * x; }

// ---------------- utility kernels ----------------
__global__ void k_zero(int* __restrict__ a, int n) {
    int i = blockIdx.x * blockDim.x + threadIdx.x;
    if (i < n) a[i] = 0;
}

__global__ void k_hist(const int* __restrict__ dst, int* __restrict__ deg, int E) {
    int i = blockIdx.x * blockDim.x + threadIdx.x;
    if (i < E) atomicAdd(&deg[dst[i]], 1);
}

// block-level exclusive scan over 1024 elements; writes per-block totals
__global__ __launch_bounds__(1024) void k_scan1(const int* __restrict__ deg, int* __restrict__ off,
                                                int* __restrict__ bsums, int N) {
    int t = threadIdx.x, b = blockIdx.x;
    int idx = b * 1024 + t;
    int v = (idx < N) ? deg[idx] : 0;
    int lane = t & 63, wid = t >> 6;
    int incl = v;
    #pragma unroll
    for (int d = 1; d < 64; d <<= 1) {
        int u = __shfl_up(incl, d);
        if (lane >= d) incl += u;
    }
    __shared__ int ws[16];
    if (lane == 63) ws[wid] = incl;
    __syncthreads();
    if (wid == 0) {
        int wv = (lane < 16) ? ws[lane] : 0;
        #pragma unroll
        for (int d = 1; d < 16; d <<= 1) {
            int u = __shfl_up(wv, d);
            if (lane >= d) wv += u;
        }
        if (lane < 16) ws[lane] = wv;  // inclusive wave sums
    }
    __syncthreads();
    int woff = (wid > 0) ? ws[wid - 1] : 0;
    if (idx < N) off[idx] = woff + incl - v;  // exclusive within block
    if (t == 0) bsums[b] = ws[15];            // block total
}

// single-block exclusive scan of up to 1024 block sums
__global__ __launch_bounds__(1024) void k_scan2(int* __restrict__ bs, int nb) {
    __shared__ int s[1024];
    int t = threadIdx.x;
    s[t] = (t < nb) ? bs[t] : 0;
    __syncthreads();
    for (int d = 1; d < 1024; d <<= 1) {
        int v = (t >= d) ? s[t - d] : 0;
        __syncthreads();
        s[t] += v;
        __syncthreads();
    }
    if (t < nb) bs[t] = t ? s[t - 1] : 0;
}

__global__ __launch_bounds__(1024) void k_scan3(int* __restrict__ off, const int* __restrict__ bs, int N) {
    int i = blockIdx.x * 1024 + threadIdx.x;
    if (i < N) off[i] += bs[blockIdx.x];
}

__global__ void k_scatter(const int* __restrict__ src, const int* __restrict__ dst,
                          const int* __restrict__ off, int* __restrict__ cur,
                          int* __restrict__ csr, int E) {
    int i = blockIdx.x * blockDim.x + threadIdx.x;
    if (i < E) {
        int d = dst[i];
        int pos = off[d] + atomicAdd(&cur[d], 1);
        csr[pos] = src[i];
    }
}

// ---------------- GEMM: XW = X[N,K] @ W[K,64], fused attention logits ----------------
// Lane = output column. Per wave: 16 rows. W transposed+swizzled in LDS:
//   Wt[c*K + ((k+4c)&(K-1))] = W[k][c]
// -> lane's b128 read of its W column chunk is 16B-aligned and bank-balanced
//    (start bank = (kbase+j+4*lane)%32, each bank hit exactly 8x = b128 minimum).
// Per 64-k chunk: Wreg[64] loaded once from LDS, reused across 16 rows (4 quads
// of 4 for FMA ILP). X row pointers forced wave-uniform via readfirstlane so the
// compiler can emit s_load (SMEM pipe, co-issues with VALU).
template <int K>
__global__ __launch_bounds__(256) void k_gemm(const float* __restrict__ X, const float* __restrict__ W,
                                              const float* __restrict__ a_s, const float* __restrict__ a_d,
                                              float* __restrict__ XW, float* __restrict__ Ssrc,
                                              float* __restrict__ Sdst, int N, int nGroups, int gridWaves) {
    __shared__ float Wt[64 * K];
    int t = threadIdx.x;
    // stage W: thread loads W[k][c0..c0+3] (coalesced dwordx4), scatters to swizzled Wt
    for (int i = t * 4; i < K * 64; i += 256 * 4) {
        const float4 v = *(const float4*)&W[i];
        int k = i >> 6;
        int c0 = i & 63;
        float vv[4] = {v.x, v.y, v.z, v.w};
        #pragma unroll
        for (int d = 0; d < 4; d++) {
            int c = c0 + d;
            Wt[c * K + ((k + 4 * c) & (K - 1))] = vv[d];
        }
    }
    __syncthreads();

    int lane = t & 63, wid = t >> 6;
    float as = a_s[lane], ad = a_d[lane];
    int gw = blockIdx.x * 4 + wid;

    for (int g = gw; g < nGroups; g += gridWaves) {
        int rbase = g * 16;
        float acc[16];
        #pragma unroll
        for (int r = 0; r < 16; r++) acc[r] = 0.f;

        for (int kc = 0; kc < K / 64; kc++) {  // dynamic loop: keeps code size bounded
            int kbase = kc * 64;
            // Wreg[j] = W[kbase+j][lane], via 16 bank-balanced b128 reads
            float Wreg[64];
            #pragma unroll
            for (int jq = 0; jq < 64; jq += 4) {
                int idx = (kbase + jq + 4 * lane) & (K - 1);
                const float4 v = *(const float4*)&Wt[lane * K + idx];
                Wreg[jq + 0] = v.x; Wreg[jq + 1] = v.y; Wreg[jq + 2] = v.z; Wreg[jq + 3] = v.w;
            }
            // 16 rows in quads of 4 (4 independent FMA chains)
            #pragma unroll
            for (int q = 0; q < 4; q++) {
                const float* xp[4];
                #pragma unroll
                for (int r = 0; r < 4; r++) {
                    int row = rbase + q * 4 + r;
                    row = row < N ? row : N - 1;
                    int rowU = __builtin_amdgcn_readfirstlane(row);
                    xp[r] = X + (size_t)rowU * K + kbase;
                }
                #pragma unroll
                for (int jj = 0; jj < 64; jj += 16) {
                    float xs[4][16];
                    #pragma unroll
                    for (int r = 0; r < 4; r++)
                        #pragma unroll
                        for (int u = 0; u < 16; u++)
                            xs[r][u] = xp[r][jj + u];
                    #pragma unroll
                    for (int u = 0; u < 16; u++)
                        #pragma unroll
                        for (int r = 0; r < 4; r++)
                            acc[q * 4 + r] += xs[r][u] * Wreg[jj + u];
                }
            }
        }

        // epilogue: write XW row + attention logit reductions
        #pragma unroll
        for (int r = 0; r < 16; r++) {
            int row = rbase + r;
            if (row < N) {
                XW[(size_t)row * 64 + lane] = acc[r];
                float vs = acc[r] * as, vd = acc[r] * ad;
                #pragma unroll
                for (int d = 32; d > 0; d >>= 1) {
                    vs += __shfl_xor(vs, d);
                    vd += __shfl_xor(vd, d);
                }
                if (lane == 0) { Ssrc[row] = vs; Sdst[row] = vd; }
            }
        }
    }
}

// ---------------- attention + aggregate: one wave per dst node ----------------
__global__ __launch_bounds__(256) void k_attn(const float* __restrict__ XW, const float* __restrict__ Ssrc,
                                              const float* __restrict__ Sdst, const int* __restrict__ csr,
                                              const int* __restrict__ off, const int* __restrict__ deg,
                                              const float* __restrict__ bias, float* __restrict__ H,
                                              int N, int do_relu) {
    int t = threadIdx.x, lane = t & 63, wid = t >> 6;
    int n = blockIdx.x * 4 + wid;
    if (n >= N) return;
    float sd = Sdst[n];
    int st = off[n], d = deg[n];

    // phase 1: max over edges (lanes parallel over edges); cache first 64 src/e in regs
    float eself = lrelu(Ssrc[n] + sd);
    float m = eself;
    int myS = 0;
    float myE = -1e30f;
    if (lane < d) {
        myS = csr[st + lane];
        myE = lrelu(Ssrc[myS] + sd);
        m = fmaxf(m, myE);
    }
    for (int i = 64 + lane; i < d; i += 64) {
        int s = csr[st + i];
        m = fmaxf(m, lrelu(Ssrc[s] + sd));
    }
    #pragma unroll
    for (int dd = 32; dd > 0; dd >>= 1) m = fmaxf(m, __shfl_xor(m, dd));

    // phase 2: serial over edges, lanes = feature dims
    float w0 = __expf(eself - m);
    float denom = w0;
    float acc = w0 * XW[(size_t)n * 64 + lane];
    int dcap = d < 64 ? d : 64;
    for (int i = 0; i < dcap; i++) {
        int s = __shfl(myS, i);
        float e = __shfl(myE, i);
        float w = __expf(e - m);
        denom += w;
        acc += w * XW[(size_t)s * 64 + lane];
    }
    for (int i = 64; i < d; i++) {
        int s = csr[st + i];
        float e = lrelu(Ssrc[s] + sd);
        float w = __expf(e - m);
        denom += w;
        acc += w * XW[(size_t)s * 64 + lane];
    }
    float o = acc / denom + bias[lane];
    if (do_relu) o = fmaxf(o, 0.f);
    H[(size_t)n * 64 + lane] = o;
}

// ---------------- head: out[i] = [h[u]; h[m]] . fcW + fcb ----------------
__global__ __launch_bounds__(256) void k_head(const float* __restrict__ H, const int* __restrict__ ui,
                                              const int* __restrict__ mi, const float* __restrict__ fcW,
                                              const float* __restrict__ fcb, float* __restrict__ out, int B) {
    int t = threadIdx.x, lane = t & 63, wid = t >> 6;
    int i = blockIdx.x * 4 + wid;
    if (i >= B) return;
    int u = ui[i], m = mi[i];
    float v = H[(size_t)u * 64 + lane] * fcW[lane] + H[(size_t)m * 64 + lane] * fcW[64 + lane];
    #pragma unroll
    for (int dd = 32; dd > 0; dd >>= 1) v += __shfl_xor(v, dd);
    if (lane == 0) out[i] = v + fcb[0];
}

extern "C" void kernel_launch(void* const* d_in, const int* in_sizes, int n_in,
                              void* d_out, int out_size, void* d_ws, size_t ws_size,
                              hipStream_t stream) {
    const float* x   = (const float*)d_in[0];
    const int*   ei  = (const int*)d_in[1];
    const int*   ui  = (const int*)d_in[2];
    const int*   mi  = (const int*)d_in[3];
    const float* W1  = (const float*)d_in[4];
    const float* as1 = (const float*)d_in[5];
    const float* ad1 = (const float*)d_in[6];
    const float* b1  = (const float*)d_in[7];
    const float* W2  = (const float*)d_in[8];
    const float* as2 = (const float*)d_in[9];
    const float* ad2 = (const float*)d_in[10];
    const float* b2  = (const float*)d_in[11];
    const float* fcW = (const float*)d_in[12];
    const float* fcb = (const float*)d_in[13];
    float* out = (float*)d_out;

    const int Hdim = in_sizes[5];            // 64
    const int FIN  = in_sizes[4] / Hdim;     // 256
    const int N    = in_sizes[0] / FIN;      // 100000
    const int E    = in_sizes[1] / 2;        // 1000000
    const int B    = in_sizes[2];            // 16384

    // workspace carve
    char* w = (char*)d_ws;
    auto alloc = [&](size_t bytes) -> void* {
        void* p = (void*)w;
        w += (bytes + 255) & ~(size_t)255;
        return p;
    };
    float* xw   = (float*)alloc((size_t)N * 64 * 4);
    float* hbuf = (float*)alloc((size_t)N * 64 * 4);
    float* ssrc = (float*)alloc((size_t)N * 4);
    float* sdst = (float*)alloc((size_t)N * 4);
    int* degcur = (int*)alloc((size_t)2 * N * 4);  // deg | cur contiguous
    int* deg = degcur;
    int* cur = degcur + N;
    int* offv  = (int*)alloc((size_t)N * 4);
    int* bsums = (int*)alloc((size_t)1024 * 4);
    int* csr   = (int*)alloc((size_t)E * 4);

    const int* esrc = ei;
    const int* edst = ei + E;

    // --- build CSR by dst (shared by both layers) ---
    k_zero<<<(2 * N + 1023) / 1024, 1024, 0, stream>>>(degcur, 2 * N);
    k_hist<<<(E + 255) / 256, 256, 0, stream>>>(edst, deg, E);
    int nb = (N + 1023) / 1024;
    k_scan1<<<nb, 1024, 0, stream>>>(deg, offv, bsums, N);
    k_scan2<<<1, 1024, 0, stream>>>(bsums, nb);
    k_scan3<<<nb, 1024, 0, stream>>>(offv, bsums, N);
    k_scatter<<<(E + 255) / 256, 256, 0, stream>>>(esrc, edst, offv, cur, csr, E);

    const int nGroups = (N + 15) / 16;  // 16 rows per wave-group
    const int gemmBlocks = 1024;
    const int gridWaves = gemmBlocks * 4;

    // --- layer 1 ---
    k_gemm<256><<<gemmBlocks, 256, 0, stream>>>(x, W1, as1, ad1, xw, ssrc, sdst, N, nGroups, gridWaves);
    k_attn<<<(N + 3) / 4, 256, 0, stream>>>(xw, ssrc, sdst, csr, offv, deg, b1, hbuf, N, 1);

    // --- layer 2 (xw buffer reused) ---
    k_gemm<64><<<gemmBlocks, 256, 0, stream>>>(hbuf, W2, as2, ad2, xw, ssrc, sdst, N, nGroups, gridWaves);
    k_attn<<<(N + 3) / 4, 256, 0, stream>>>(xw, ssrc, sdst, csr, offv, deg, b2, hbuf, N, 0);

    // --- head ---
    k_head<<<(B + 3) / 4, 256, 0, stream>>>(hbuf, ui, mi, fcW, fcb, out, B);
}